// Round 6
// baseline (593.942 us; speedup 1.0000x reference)
//
#include <hip/hip_runtime.h>
#include <math.h>

// ---------------- problem constants ----------------
constexpr int   NN  = 100000;    // nodes
constexpr int   EE  = 1600000;   // edges
constexpr int   HH  = 128;       // hidden / in_channels
constexpr int   GG  = 128;       // graphs
constexpr float EPSV = 1e-5f;
constexpr int   NSH = 8;         // XCD shards (blockIdx&7 -> XCD heuristic)
constexpr int   SHN = NN / NSH;  // 12500 nodes per shard
constexpr int   CAP = 210000;    // per-shard bin capacity (E/8=200k, +5 sigma)

typedef __attribute__((ext_vector_type(8))) short  short8;
typedef __attribute__((ext_vector_type(4))) float  f32x4;
typedef __attribute__((ext_vector_type(2))) float  v2f;

__device__ __forceinline__ unsigned short f2bf(float f) {
    union { float f; unsigned u; } v; v.f = f;
    unsigned r = v.u + 0x7FFF + ((v.u >> 16) & 1);   // round-to-nearest-even
    return (unsigned short)(r >> 16);
}
__device__ __forceinline__ float bf2f(unsigned short b) {
    union { unsigned u; float f; } v; v.u = ((unsigned)b) << 16;
    return v.f;
}

// ---------------- workspace layout ----------------
constexpr size_t A256(size_t x) { return (x + 255) & ~(size_t)255; }
constexpr size_t OFF_DEG = 0;                                       // N ints (edge counts)
constexpr size_t OFF_TL  = OFF_DEG + (size_t)NN * 4;                // 8 uints bin tails (same memset as deg)
constexpr size_t OFF_DNV = A256(OFF_TL  + 8 * 4);                   // N floats dinv
constexpr size_t OFF_RP  = A256(OFF_DNV + (size_t)NN * 4);          // (N+1) ints
constexpr size_t OFF_CUR = A256(OFF_RP  + (size_t)(NN + 1) * 4);    // N ints (running cursor)
constexpr size_t OFF_SRC = A256(OFF_CUR + (size_t)NN * 4);          // E ints sorted src
constexpr size_t OFF_BIN = A256(OFF_SRC + (size_t)EE * 4);          // 8*CAP uints packed bins
constexpr size_t OFF_BS  = A256(OFF_BIN + (size_t)8 * CAP * 4);     // 512 ints
constexpr size_t OFF_XB  = A256(OFF_BS  + 512 * 4);                 // N*H bf16 (x)
constexpr size_t OFF_HW  = A256(OFF_XB  + (size_t)NN * HH * 2);     // N*H bf16 (h@W)
constexpr size_t OFF_H0  = A256(OFF_HW  + (size_t)NN * HH * 2);     // N*H bf16 (h)
constexpr size_t OFF_PL  = A256(OFF_H0  + (size_t)NN * HH * 2);     // G*H f32 pooled + G f32 cnt

// ---------------- phase A: bin edges by dst-shard, packed 31-bit ----------------
// R5 lesson: direct sharded scatter still wrote 73 MB for a 6.4 MB array --
// the 12.8 MB edge stream flowing through each L2 evicted partial ssrc lines.
// Fix: bin once into per-shard arrays (packed u32: dstLocal<<17 | src), then
// count/scatter read ONLY their shard's 800 KB bin -> L2 working set ~1.6 MB.
__global__ __launch_bounds__(256) void k_bin(const int* __restrict__ src,
                                             const int* __restrict__ dst,
                                             unsigned* __restrict__ bins,
                                             unsigned* __restrict__ gtail) {
    __shared__ unsigned sbin[8][1024];
    __shared__ unsigned scnt[8];
    __shared__ unsigned sbase[8];
    int t = threadIdx.x;
    if (t < 8) scnt[t] = 0;
    __syncthreads();
    int i = blockIdx.x * 256 + t;            // int4 index
    const int nvec = EE / 4;                 // 400000
    if (i < nvec) {
        int4 d = ((const int4*)dst)[i];
        int4 s = ((const int4*)src)[i];
        int dd[4] = {d.x, d.y, d.z, d.w};
        int ss[4] = {s.x, s.y, s.z, s.w};
#pragma unroll
        for (int c = 0; c < 4; ++c) {
            int sh = dd[c] / SHN;
            unsigned p = atomicAdd(&scnt[sh], 1u);
            sbin[sh][p] = ((unsigned)(dd[c] - sh * SHN) << 17) | (unsigned)ss[c];
        }
    }
    __syncthreads();
    if (t < 8) sbase[t] = atomicAdd(&gtail[t], scnt[t]);
    __syncthreads();
    for (int s = 0; s < 8; ++s) {
        unsigned cnt = scnt[s], base = sbase[s];
        if (base >= (unsigned)CAP) continue;               // safety clamp
        if (base + cnt > (unsigned)CAP) cnt = CAP - base;  // (never in practice)
        for (unsigned j = t; j < cnt; j += 256)
            bins[(size_t)s * CAP + base + j] = sbin[s][j];
    }
}

// ---------------- degree count from bins (XCD-local) ----------------
__global__ __launch_bounds__(256) void k_count2(const unsigned* __restrict__ bins,
                                                const unsigned* __restrict__ gtail,
                                                int* __restrict__ deg) {
    int shard = blockIdx.x & 7;
    unsigned chunk = blockIdx.x >> 3;
    int lo = SHN * shard;
    unsigned m = gtail[shard];
    const unsigned* b = bins + (size_t)shard * CAP;
    for (unsigned i = chunk * 256 + threadIdx.x; i < m; i += 256 * 256)
        atomicAdd(&deg[lo + (int)(b[i] >> 17)], 1);
}

__global__ __launch_bounds__(1024) void k_scan_local(const int* __restrict__ deg,
                                                     int* __restrict__ row_ptr,
                                                     int* __restrict__ bsum) {
    __shared__ int s[1024];
    int t = threadIdx.x;
    int i = blockIdx.x * 1024 + t;
    int v = (i < NN) ? deg[i] : 0;
    s[t] = v;
    __syncthreads();
    for (int off = 1; off < 1024; off <<= 1) {
        int u = (t >= off) ? s[t - off] : 0;
        __syncthreads();
        s[t] += u;
        __syncthreads();
    }
    if (i < NN) row_ptr[i] = s[t] - v;
    if (t == 1023) bsum[blockIdx.x] = s[1023];
}

__global__ void k_scan_blocks(int* __restrict__ bsum, int nb) {
    __shared__ int s[128];
    int t = threadIdx.x;
    int v = (t < nb) ? bsum[t] : 0;
    s[t] = v;
    __syncthreads();
    for (int off = 1; off < 128; off <<= 1) {
        int u = (t >= off) ? s[t - off] : 0;
        __syncthreads();
        s[t] += u;
        __syncthreads();
    }
    if (t < nb) bsum[t] = s[t] - v;
}

// final row_ptr; pre-fill scatter cursor; fused dinv (saves a kernel)
__global__ void k_scan_add(int* __restrict__ row_ptr, const int* __restrict__ bsum,
                           int* __restrict__ cursor, const int* __restrict__ deg,
                           float* __restrict__ dinv) {
    int i = blockIdx.x * 256 + threadIdx.x;
    if (i < NN) {
        int v = row_ptr[i] + bsum[i >> 10];
        row_ptr[i] = v;
        cursor[i] = v;
        dinv[i] = rsqrtf((float)(deg[i] + 1));  // +1 self-loop
    }
    if (i == 0) row_ptr[NN] = EE;
}

// ---------------- scatter from bins (XCD-local reads AND writes) ----------------
__global__ __launch_bounds__(256) void k_scatter2(const unsigned* __restrict__ bins,
                                                  const unsigned* __restrict__ gtail,
                                                  int* __restrict__ cursor,
                                                  int* __restrict__ ssrc) {
    int shard = blockIdx.x & 7;
    unsigned chunk = blockIdx.x >> 3;
    int lo = SHN * shard;
    unsigned m = gtail[shard];
    const unsigned* b = bins + (size_t)shard * CAP;
    for (unsigned i = chunk * 256 + threadIdx.x; i < m; i += 256 * 256) {
        unsigned u = b[i];
        int dd = lo + (int)(u >> 17);
        int p = atomicAdd(&cursor[dd], 1);
        ssrc[p] = (int)(u & 0x1FFFFu);
    }
}

// ---------------- x -> bf16 ----------------
__global__ void k_cvt(const float* __restrict__ x, unsigned short* __restrict__ xb) {
    int i = blockIdx.x * 256 + threadIdx.x;
    if (i < NN * (HH / 4)) {
        float4 v = ((const float4*)x)[i];
        ushort4 o;
        o.x = f2bf(v.x); o.y = f2bf(v.y); o.z = f2bf(v.z); o.w = f2bf(v.w);
        ((ushort4*)xb)[i] = o;
    }
}

// ---------------- GEMM: C[N,128] = A[N,128] @ W[128,128], MFMA bf16, split-W ----------------
__global__ __launch_bounds__(256) void gemm_mfma(const unsigned short* __restrict__ A,
                                                 const float* __restrict__ W,
                                                 unsigned short* __restrict__ C, int nrows) {
    __shared__ unsigned short smem[2 * 64 * 136];  // WtH | WtL ; reused as Cs[128][68]
    unsigned short* WtH = smem;
    unsigned short* WtL = smem + 64 * 136;

    int t = threadIdx.x;
    int row0 = blockIdx.x * 128;
    int c0   = blockIdx.y * 64;

    for (int idx = t; idx < 64 * 128; idx += 256) {
        int k = idx >> 6, c = idx & 63;
        float w = W[k * 128 + c0 + c];
        unsigned short hb = f2bf(w);
        unsigned short lb = f2bf(w - bf2f(hb));
        WtH[c * 136 + k] = hb;
        WtL[c * 136 + k] = lb;
    }
    __syncthreads();

    int wv = t >> 6, lane = t & 63, m = lane & 15, q = lane >> 4;
    long rowA = row0 + wv * 32 + m;
    long rowB = rowA + 16;

    f32x4 acc[2][4] = {};
    for (int kc = 0; kc < 4; ++kc) {
        int ko = kc * 32 + q * 8;
        short8 a0 = {}, a1 = {};
        if (rowA < nrows) a0 = *(const short8*)(A + rowA * 128 + ko);
        if (rowB < nrows) a1 = *(const short8*)(A + rowB * 128 + ko);
#pragma unroll
        for (int ct = 0; ct < 4; ++ct) {
            short8 bh = *(const short8*)(WtH + (ct * 16 + m) * 136 + ko);
            short8 bl = *(const short8*)(WtL + (ct * 16 + m) * 136 + ko);
            acc[0][ct] = __builtin_amdgcn_mfma_f32_16x16x32_bf16(a0, bh, acc[0][ct], 0, 0, 0);
            acc[0][ct] = __builtin_amdgcn_mfma_f32_16x16x32_bf16(a0, bl, acc[0][ct], 0, 0, 0);
            acc[1][ct] = __builtin_amdgcn_mfma_f32_16x16x32_bf16(a1, bh, acc[1][ct], 0, 0, 0);
            acc[1][ct] = __builtin_amdgcn_mfma_f32_16x16x32_bf16(a1, bl, acc[1][ct], 0, 0, 0);
        }
    }

    __syncthreads();
    unsigned short* Cs = smem;  // [128][68]
#pragma unroll
    for (int rt = 0; rt < 2; ++rt)
#pragma unroll
        for (int ct = 0; ct < 4; ++ct)
#pragma unroll
            for (int r = 0; r < 4; ++r) {
                int rl = wv * 32 + rt * 16 + q * 4 + r;
                Cs[rl * 68 + ct * 16 + m] = f2bf(acc[rt][ct][r]);
            }
    __syncthreads();
    for (int idx = t; idx < 128 * 16; idx += 256) {
        int row = idx >> 4, ch = idx & 15;
        long grow = row0 + row;
        if (grow < nrows)
            *(ushort4*)(C + grow * 128 + c0 + ch * 4) = *(const ushort4*)(Cs + row * 68 + ch * 4);
    }
}

// ---------------- aggregate + bias + BN + ReLU ----------------
// one edge per FULL wave; 64-edge metadata preload; readlane -> SGPR row base;
// 2 ch/lane packed float2 FMA; pad = self row with ds=0.
__global__ __launch_bounds__(256) void k_agg(const unsigned short* __restrict__ hw,
                                             const int* __restrict__ rp,
                                             const int* __restrict__ ssrc,
                                             const float* __restrict__ dinv,
                                             const float* __restrict__ bsl,
                                             const float* __restrict__ gamma,
                                             const float* __restrict__ beta,
                                             const float* __restrict__ rm,
                                             const float* __restrict__ rv,
                                             unsigned short* __restrict__ out) {
    int lane = threadIdx.x & 63;
    int c2   = lane * 2;                       // 2 channels per lane
    int n = blockIdx.x * 4 + (threadIdx.x >> 6);
    if (n >= NN) return;
    int beg = rp[n], end = rp[n + 1];

    v2f acc0 = {0.f, 0.f}, acc1 = {0.f, 0.f};

    for (int chunk = beg; chunk < end; chunk += 64) {
        int l = chunk + lane;
        bool valid = (l < end);
        int   e  = valid ? ssrc[l] : n;        // pad: self row (harmless, ds=0)
        float dv = valid ? dinv[e] : 0.f;
        int cnt = end - chunk;
        if (cnt > 64) cnt = 64;
        for (int jb = 0; jb < cnt; jb += 8) {
#pragma unroll
            for (int j = 0; j < 8; ++j) {
                int s    = __builtin_amdgcn_readlane(e, jb + j);
                float ds = __int_as_float(
                               __builtin_amdgcn_readlane(__float_as_int(dv), jb + j));
                unsigned u = *(const unsigned*)(hw + (size_t)s * HH + c2);
                v2f vv;
                vv.x = __int_as_float((int)(u << 16));
                vv.y = __int_as_float((int)(u & 0xffff0000u));
                v2f d2 = {ds, ds};
                if (j & 1) acc1 += d2 * vv;
                else       acc0 += d2 * vv;
            }
        }
    }
    v2f a = acc0 + acc1;

    // self-loop
    float di = dinv[n];
    {
        unsigned u = *(const unsigned*)(hw + (size_t)n * HH + c2);
        v2f vv;
        vv.x = __int_as_float((int)(u << 16));
        vv.y = __int_as_float((int)(u & 0xffff0000u));
        v2f d2 = {di, di};
        a += d2 * vv;
    }
    a.x *= di;
    a.y *= di;

    float g0 = gamma[c2],   g1 = gamma[c2 + 1];
    float r0 = rv[c2],      r1 = rv[c2 + 1];
    float s0 = g0 * rsqrtf(r0 + EPSV);
    float s1 = g1 * rsqrtf(r1 + EPSV);
    float b0 = fmaf(bsl[c2]     - rm[c2],     s0, beta[c2]);
    float b1 = fmaf(bsl[c2 + 1] - rm[c2 + 1], s1, beta[c2 + 1]);
    float y0 = fmaxf(fmaf(a.x, s0, b0), 0.f);
    float y1 = fmaxf(fmaf(a.y, s1, b1), 0.f);
    ushort2 o;
    o.x = f2bf(y0);
    o.y = f2bf(y1);
    *(ushort2*)(out + (size_t)n * HH + c2) = o;
}

// ---------------- global mean pool (batch sorted, bf16 input) ----------------
__global__ __launch_bounds__(128) void k_pool(const unsigned short* __restrict__ h,
                                              const int* __restrict__ batch,
                                              float* __restrict__ pooled,
                                              float* __restrict__ cnt) {
    int t = threadIdx.x;
    const int chunk = (NN + 1023) / 1024;
    int n0 = blockIdx.x * chunk;
    if (n0 >= NN) return;
    int n1 = n0 + chunk;
    if (n1 > NN) n1 = NN;
    int cur = batch[n0];
    float acc = 0.f;
    int k = 0;
    for (int n = n0; n < n1; ++n) {
        int b = batch[n];
        if (b != cur) {
            atomicAdd(&pooled[(size_t)cur * 128 + t], acc);
            if (t == 0) atomicAdd(&cnt[cur], (float)k);
            acc = 0.f; k = 0; cur = b;
        }
        acc += bf2f(h[(size_t)n * 128 + t]);
        ++k;
    }
    atomicAdd(&pooled[(size_t)cur * 128 + t], acc);
    if (t == 0) atomicAdd(&cnt[cur], (float)k);
}

// ---------------- LSTM (single step, h0=c0=0) + FC ----------------
__global__ __launch_bounds__(128) void k_head(const float* __restrict__ pooled,
                                              const float* __restrict__ cnt,
                                              const float* __restrict__ W_ih,
                                              const float* __restrict__ b_ih,
                                              const float* __restrict__ b_hh,
                                              const float* __restrict__ W_fc,
                                              const float* __restrict__ b_fc,
                                              float* __restrict__ out) {
    __shared__ float pm[128];
    __shared__ float gate[512];
    __shared__ float hn[128];
    int g = blockIdx.x, t = threadIdx.x;
    float cdiv = fmaxf(cnt[g], 1.0f);
    pm[t] = pooled[(size_t)g * 128 + t] / cdiv;
    __syncthreads();
    for (int j = t; j < 512; j += 128) {
        float acc = b_ih[j] + b_hh[j];
        const float* w = W_ih + (size_t)j * 128;
#pragma unroll 8
        for (int k = 0; k < 128; ++k) acc = fmaf(pm[k], w[k], acc);
        gate[j] = acc;
    }
    __syncthreads();
    {
        float gi = gate[t], gg = gate[256 + t], go = gate[384 + t];
        float cc = (1.f / (1.f + expf(-gi))) * tanhf(gg);
        hn[t] = (1.f / (1.f + expf(-go))) * tanhf(cc);
    }
    __syncthreads();
    if (t < 16) {
        float acc = b_fc[t];
        const float* w = W_fc + (size_t)t * 128;
#pragma unroll 8
        for (int k = 0; k < 128; ++k) acc = fmaf(hn[k], w[k], acc);
        out[(size_t)g * 16 + t] = acc;
    }
}

// ---------------- launch ----------------
extern "C" void kernel_launch(void* const* d_in, const int* in_sizes, int n_in,
                              void* d_out, int out_size, void* d_ws, size_t ws_size,
                              hipStream_t stream) {
    const float* x      = (const float*)d_in[0];
    const int*   ei     = (const int*)d_in[1];
    const int*   src    = ei;
    const int*   dst    = ei + EE;
    const int*   batch  = (const int*)d_in[2];
    const float* Ws     = (const float*)d_in[3];
    const float* bs     = (const float*)d_in[4];
    const float* gammas = (const float*)d_in[5];
    const float* betas  = (const float*)d_in[6];
    const float* rms    = (const float*)d_in[7];
    const float* rvs    = (const float*)d_in[8];
    const float* W_ih   = (const float*)d_in[9];
    // d_in[10] = W_hh (unused: h0 = 0)
    const float* b_ih   = (const float*)d_in[11];
    const float* b_hh   = (const float*)d_in[12];
    const float* W_fc   = (const float*)d_in[13];
    const float* b_fc   = (const float*)d_in[14];
    float* out = (float*)d_out;

    char* w = (char*)d_ws;
    int*            deg    = (int*)(w + OFF_DEG);
    unsigned*       gtail  = (unsigned*)(w + OFF_TL);
    float*          dinv   = (float*)(w + OFF_DNV);
    int*            rp     = (int*)(w + OFF_RP);
    int*            cursor = (int*)(w + OFF_CUR);
    int*            ssrc   = (int*)(w + OFF_SRC);
    unsigned*       bins   = (unsigned*)(w + OFF_BIN);
    int*            bsum   = (int*)(w + OFF_BS);
    unsigned short* xb     = (unsigned short*)(w + OFF_XB);
    unsigned short* hwb    = (unsigned short*)(w + OFF_HW);
    unsigned short* h0     = (unsigned short*)(w + OFF_H0);
    float*          pooled = (float*)(w + OFF_PL);
    float*          cntb   = pooled + (size_t)GG * HH;

    hipMemsetAsync(deg, 0, (size_t)NN * 4 + 8 * 4, stream);  // deg + gtail contiguous
    hipMemsetAsync(pooled, 0, ((size_t)GG * HH + GG) * 4, stream);

    k_bin<<<(EE / 4 + 255) / 256, 256, 0, stream>>>(src, dst, bins, gtail);
    k_count2<<<2048, 256, 0, stream>>>(bins, gtail, deg);
    const int nscan = (NN + 1023) / 1024;
    k_scan_local<<<nscan, 1024, 0, stream>>>(deg, rp, bsum);
    k_scan_blocks<<<1, 128, 0, stream>>>(bsum, nscan);
    k_scan_add<<<(NN + 255) / 256, 256, 0, stream>>>(rp, bsum, cursor, deg, dinv);
    k_scatter2<<<2048, 256, 0, stream>>>(bins, gtail, cursor, ssrc);
    k_cvt<<<(NN * 32 + 255) / 256, 256, 0, stream>>>(x, xb);

    const unsigned short* hin = xb;
    dim3 ggrid((NN + 127) / 128, 2);
    for (int l = 0; l < 3; ++l) {
        gemm_mfma<<<ggrid, 256, 0, stream>>>(hin, Ws + (size_t)l * 128 * 128, hwb, NN);
        k_agg<<<(NN + 3) / 4, 256, 0, stream>>>(hwb, rp, ssrc, dinv,
                                                bs + l * 128, gammas + l * 128, betas + l * 128,
                                                rms + l * 128, rvs + l * 128, h0);
        hin = h0;
    }
    k_pool<<<1024, 128, 0, stream>>>(h0, batch, pooled, cntb);
    k_head<<<GG, 128, 0, stream>>>(pooled, cntb, W_ih, b_ih, b_hh, W_fc, b_fc, out);
}